// Round 15
// baseline (324.990 us; speedup 1.0000x reference)
//
#include <hip/hip_runtime.h>
#include <hip/hip_fp16.h>
#include <math.h>

#define F 128
#define D 64
#define BSHIFT 9            // bin = row >> 9 (512 rows/bin); nbins <= 256 required
#define CHUNK 4096          // edges per pass-A block (LDS counting sort)
#define HCHUNK 8192         // edges per histogram block
#define BCAP 16384          // pass-B LDS edge capacity (mean 8192, overflow ~90 sigma)

// ---------- 1. per-feature sum / sumsq over rows ----------
__global__ __launch_bounds__(256) void k_stats(const float* __restrict__ x,
                                               float* __restrict__ stats, int N) {
    int tid = threadIdx.x;
    int f = tid & 127;
    int rowOff = tid >> 7;
    float s = 0.f, sq = 0.f;
    for (int r = blockIdx.x * 2 + rowOff; r < N; r += gridDim.x * 2) {
        float v = x[(size_t)r * F + f];
        s += v; sq += v * v;
    }
    __shared__ float ls[256], lq[256];
    ls[tid] = s; lq[tid] = sq;
    __syncthreads();
    if (tid < 128) {
        atomicAdd(&stats[f],       ls[tid] + ls[tid + 128]);
        atomicAdd(&stats[128 + f], lq[tid] + lq[tid + 128]);
    }
}

// ---------- 2. fold BN into kernel ----------
__global__ __launch_bounds__(128) void k_prep(const float* __restrict__ stats,
                                              const float* __restrict__ W,
                                              float* __restrict__ Kp,
                                              float* __restrict__ bias, int N) {
    __shared__ float mean_s[F], rs_s[F];
    int t = threadIdx.x;
    float invN = 1.0f / (float)N;
    float m   = stats[t] * invN;
    float var = stats[128 + t] * invN - m * m;
    float rs  = rsqrtf(var + 1e-3f);
    mean_s[t] = m; rs_s[t] = rs;
    __syncthreads();
    for (int i = 0; i < 64; ++i) {
        int idx = t + 128 * i;
        int f = idx >> 6;
        Kp[idx] = rs_s[f] * W[idx];
    }
    if (t < D) {
        float b = 0.f;
        for (int f = 0; f < F; ++f) b -= mean_s[f] * rs_s[f] * W[f * D + t];
        bias[t] = b;
    }
}

// ---------- 3. h = x @ Kp + bias  (fp16 output; Kp/bias direct from L2; no barriers) ----------
__global__ __launch_bounds__(256) void k_gemm(const float* __restrict__ x,
                                              const float* __restrict__ Kp,
                                              const float* __restrict__ bias,
                                              __half* __restrict__ h, int N) {
    __shared__ float4 xs4[4][256];     // wave-private slices: no __syncthreads needed
    int tid = threadIdx.x;
    int wave = tid >> 6, lane = tid & 63;
    int base = blockIdx.x * 32 + wave * 8;
    const float4* xsrc = (const float4*)(x + (size_t)base * F);
    xs4[wave][lane]       = xsrc[lane];
    xs4[wave][lane + 64]  = xsrc[lane + 64];
    xs4[wave][lane + 128] = xsrc[lane + 128];
    xs4[wave][lane + 192] = xsrc[lane + 192];

    float bv = bias[lane];
    float acc[8];
    #pragma unroll
    for (int r = 0; r < 8; ++r) acc[r] = bv;

    const float4* xrow = xs4[wave];
    #pragma unroll 4
    for (int f4 = 0; f4 < 32; ++f4) {
        float k0 = Kp[(4 * f4 + 0) * D + lane];      // L2-hot (32 KB shared by all blocks)
        float k1 = Kp[(4 * f4 + 1) * D + lane];
        float k2 = Kp[(4 * f4 + 2) * D + lane];
        float k3 = Kp[(4 * f4 + 3) * D + lane];
        #pragma unroll
        for (int r = 0; r < 8; ++r) {
            float4 a = xrow[r * 32 + f4];            // LDS broadcast
            acc[r] += a.x * k0 + a.y * k1 + a.z * k2 + a.w * k3;
        }
    }
    #pragma unroll
    for (int r = 0; r < 8; ++r)
        h[(size_t)(base + r) * D + lane] = __float2half(acc[r]);
}

// ---------- 4a. bin histogram ----------
__global__ __launch_bounds__(256) void k_binhist(const int* __restrict__ rows,
                                                 int* __restrict__ bincnt, int E) {
    __shared__ int lh[256];
    int tid = threadIdx.x;
    lh[tid] = 0;
    __syncthreads();
    int e0 = blockIdx.x * HCHUNK, e1 = min(E, e0 + HCHUNK);
    for (int e = e0 + tid; e < e1; e += 256)
        atomicAdd(&lh[rows[e] >> BSHIFT], 1);
    __syncthreads();
    int c = lh[tid];
    if (c > 0) atomicAdd(&bincnt[tid], c);
}

// ---------- 4b. scan 256 bin counts -> binstart[257], bincur ----------
__global__ __launch_bounds__(256) void k_binscan(const int* __restrict__ bincnt,
                                                 int* __restrict__ binstart,
                                                 int* __restrict__ bincur, int E) {
    __shared__ int s0[256], s1[256];
    int t = threadIdx.x;
    int v = bincnt[t];
    s0[t] = v;
    __syncthreads();
    int* a = s0; int* b = s1;
    for (int off = 1; off < 256; off <<= 1) {
        int val = a[t] + ((t >= off) ? a[t - off] : 0);
        b[t] = val;
        __syncthreads();
        int* tmp = a; a = b; b = tmp;
    }
    int excl = a[t] - v;
    binstart[t] = excl;
    bincur[t]   = excl;
    if (t == 255) binstart[256] = E;
}

// ---------- 4c. pass A: block-local LDS counting sort by bin, coalesced flush ----------
__global__ __launch_bounds__(256) void k_blocksortA(const int* __restrict__ rows,
                                                    const int* __restrict__ cols,
                                                    const float* __restrict__ ev,
                                                    int* __restrict__ bincur,
                                                    float4* __restrict__ ce_tmp, int E) {
    __shared__ int lcnt[256], lofs[256], gbase[256];
    __shared__ int sA[256], sB[256];
    __shared__ unsigned short binof[CHUNK];
    __shared__ float4 buf[CHUNK];                     // 64 KB
    int tid = threadIdx.x;
    int e0 = blockIdx.x * CHUNK, e1 = min(E, e0 + CHUNK);

    lcnt[tid] = 0;
    __syncthreads();
    for (int e = e0 + tid; e < e1; e += 256)
        atomicAdd(&lcnt[rows[e] >> BSHIFT], 1);
    __syncthreads();
    sA[tid] = lcnt[tid];
    __syncthreads();
    int* a = sA; int* b = sB;
    for (int off = 1; off < 256; off <<= 1) {
        int val = a[tid] + ((tid >= off) ? a[tid - off] : 0);
        b[tid] = val;
        __syncthreads();
        int* tmp = a; a = b; b = tmp;
    }
    lofs[tid] = a[tid] - lcnt[tid];
    __syncthreads();
    lcnt[tid] = lofs[tid];                            // running cursor
    __syncthreads();
    for (int e = e0 + tid; e < e1; e += 256) {
        int r = rows[e];
        int bin = r >> BSHIFT;
        int slot = atomicAdd(&lcnt[bin], 1);
        buf[slot] = make_float4(__int_as_float(r), __int_as_float(cols[e]), ev[e], 0.f);
        binof[slot] = (unsigned short)bin;
    }
    __syncthreads();
    {
        int c = lcnt[tid] - lofs[tid];
        if (c > 0) gbase[tid] = atomicAdd(&bincur[tid], c);
    }
    __syncthreads();
    int n = e1 - e0;
    for (int s = tid; s < n; s += 256) {
        int bin = binof[s];
        ce_tmp[gbase[bin] + (s - lofs[bin])] = buf[s];
    }
}

// ---------- 4d. pass B: row-sort + FUSED SOFTMAX; ce = (col, normalized weight) ----------
__global__ __launch_bounds__(256) void k_binsortB(const float4* __restrict__ ce_tmp,
                                                  const int* __restrict__ binstart,
                                                  int* __restrict__ startm,
                                                  int* __restrict__ cnt,
                                                  float2* __restrict__ ce, int N, int E) {
    __shared__ float2 lbuf[BCAP];                     // 128 KB
    __shared__ int hist[512], ofs[512], ps[256], ps2[256];
    int tid = threadIdx.x;
    int r0 = blockIdx.x << BSHIFT;
    int gbeg = binstart[blockIdx.x];
    int gend = binstart[blockIdx.x + 1];
    int count = gend - gbeg;

    hist[tid] = 0; hist[tid + 256] = 0;
    __syncthreads();
    for (int k = tid; k < count; k += 256)
        atomicAdd(&hist[__float_as_int(ce_tmp[gbeg + k].x) - r0], 1);
    __syncthreads();
    int h0 = hist[2 * tid], h1 = hist[2 * tid + 1];
    ps[tid] = h0 + h1;
    __syncthreads();
    int* a = ps; int* b = ps2;
    for (int off = 1; off < 256; off <<= 1) {
        int val = a[tid] + ((tid >= off) ? a[tid - off] : 0);
        b[tid] = val;
        __syncthreads();
        int* tmp = a; a = b; b = tmp;
    }
    int pexcl = a[tid] - (h0 + h1);
    ofs[2 * tid]     = pexcl;
    ofs[2 * tid + 1] = pexcl + h0;
    __syncthreads();
    for (int i = tid; i < 512; i += 256) {
        int r = r0 + i;
        if (r < N) { startm[r] = gbeg + ofs[i]; cnt[r] = hist[i]; }
    }
    __syncthreads();
    hist[2 * tid]     = ofs[2 * tid];
    hist[2 * tid + 1] = ofs[2 * tid + 1];
    __syncthreads();
    if (count <= BCAP) {
        for (int k = tid; k < count; k += 256) {
            float4 t4 = ce_tmp[gbeg + k];
            int slot = atomicAdd(&hist[__float_as_int(t4.x) - r0], 1);
            lbuf[slot] = make_float2(t4.y, t4.z);
        }
        __syncthreads();
        // fused per-row softmax in LDS (after placement, hist[i] = row end)
        for (int i = tid; i < 512; i += 256) {
            int beg = ofs[i], endd = hist[i];
            if (endd > beg) {
                float mx = -INFINITY;
                for (int k = beg; k < endd; ++k) mx = fmaxf(mx, lbuf[k].y);
                float ss = 0.f;
                for (int k = beg; k < endd; ++k) ss += __expf(lbuf[k].y - mx);
                float inv = 1.f / ss;
                for (int k = beg; k < endd; ++k)
                    lbuf[k].y = __expf(lbuf[k].y - mx) * inv;
            }
        }
        __syncthreads();
        for (int k = tid; k < count; k += 256)
            ce[gbeg + k] = lbuf[k];                   // fully coalesced
    } else {
        // overflow fallback (statistically ~impossible): direct in L2
        for (int k = tid; k < count; k += 256) {
            float4 t4 = ce_tmp[gbeg + k];
            int slot = atomicAdd(&hist[__float_as_int(t4.x) - r0], 1);
            ce[gbeg + slot] = make_float2(t4.y, t4.z);
        }
        __syncthreads();
        for (int i = tid; i < 512; i += 256) {
            int beg = gbeg + ofs[i], endd = gbeg + hist[i];
            if (endd > beg) {
                float mx = -INFINITY;
                for (int k = beg; k < endd; ++k) mx = fmaxf(mx, ce[k].y);
                float ss = 0.f;
                for (int k = beg; k < endd; ++k) ss += __expf(ce[k].y - mx);
                float inv = 1.f / ss;
                for (int k = beg; k < endd; ++k)
                    ce[k].y = __expf(ce[k].y - mx) * inv;
            }
        }
    }
}

// ---------- 5. pure gather-MAC + tanh (weights precomputed; scalar edge loads) ----------
__global__ __launch_bounds__(256) void k_agg(const int* __restrict__ startm,
                                             const int* __restrict__ cnt,
                                             const float2* __restrict__ ce,
                                             const __half* __restrict__ h,
                                             float* __restrict__ out, int N) {
    int wid = threadIdx.x >> 6, lane = threadIdx.x & 63;
    int r = blockIdx.x * 4 + wid;
    if (r >= N) return;
    int base = __builtin_amdgcn_readfirstlane(startm[r]);   // SGPR
    int nd   = __builtin_amdgcn_readfirstlane(cnt[r]);      // SGPR
    const float2* cep = ce + base;                          // uniform pointer -> s_load

    float acc = 0.f;
    int j = 0;
    for (; j + 8 <= nd; j += 8) {                           // 8 gathers in flight
        float2 t0 = cep[j + 0], t1 = cep[j + 1], t2 = cep[j + 2], t3 = cep[j + 3];
        float2 t4 = cep[j + 4], t5 = cep[j + 5], t6 = cep[j + 6], t7 = cep[j + 7];
        const __half* p0 = h + (size_t)__float_as_int(t0.x) * D;  // scalar base + lane
        const __half* p1 = h + (size_t)__float_as_int(t1.x) * D;
        const __half* p2 = h + (size_t)__float_as_int(t2.x) * D;
        const __half* p3 = h + (size_t)__float_as_int(t3.x) * D;
        const __half* p4 = h + (size_t)__float_as_int(t4.x) * D;
        const __half* p5 = h + (size_t)__float_as_int(t5.x) * D;
        const __half* p6 = h + (size_t)__float_as_int(t6.x) * D;
        const __half* p7 = h + (size_t)__float_as_int(t7.x) * D;
        acc += t0.y * __half2float(p0[lane]) + t1.y * __half2float(p1[lane])
             + t2.y * __half2float(p2[lane]) + t3.y * __half2float(p3[lane]);
        acc += t4.y * __half2float(p4[lane]) + t5.y * __half2float(p5[lane])
             + t6.y * __half2float(p6[lane]) + t7.y * __half2float(p7[lane]);
    }
    for (; j < nd; ++j) {
        float2 t = cep[j];
        acc += t.y * __half2float(h[(size_t)__float_as_int(t.x) * D + lane]);
    }
    out[(size_t)r * D + lane] = tanhf(acc);
}

// ---------- fallback path (atomic scatter), used only if ws too small or N too big ----------
__global__ __launch_bounds__(256) void k_rowmax(const float* __restrict__ ev,
                                                const int* __restrict__ rows,
                                                float* __restrict__ rmax, int E) {
    int i = blockIdx.x * 256 + threadIdx.x;
    if (i < E)
        atomicMax((unsigned int*)&rmax[rows[i]], __float_as_uint(ev[i]));
}

__global__ __launch_bounds__(256) void k_rowsum(const float* __restrict__ ev,
                                                const int* __restrict__ rows,
                                                const float* __restrict__ rmax,
                                                float* __restrict__ rsum, int E) {
    int i = blockIdx.x * 256 + threadIdx.x;
    if (i < E) {
        int r = rows[i];
        atomicAdd(&rsum[r], __expf(ev[i] - rmax[r]));
    }
}

__global__ __launch_bounds__(256) void k_scatter(const float* __restrict__ ev,
                                                 const int* __restrict__ rows,
                                                 const int* __restrict__ cols,
                                                 const float* __restrict__ rmax,
                                                 const float* __restrict__ rsum,
                                                 const __half* __restrict__ h,
                                                 float* __restrict__ out, int E) {
    int lane = threadIdx.x & 63;
    int e = blockIdx.x * 4 + (threadIdx.x >> 6);
    if (e < E) {
        int r = rows[e], c = cols[e];
        float w = __expf(ev[e] - rmax[r]) / rsum[r];
        atomicAdd(&out[(size_t)r * D + lane], w * __half2float(h[(size_t)c * D + lane]));
    }
}

__global__ __launch_bounds__(256) void k_tanh(float* __restrict__ out, int n4) {
    for (int i = blockIdx.x * 256 + threadIdx.x; i < n4; i += gridDim.x * 256) {
        float4 v = ((float4*)out)[i];
        v.x = tanhf(v.x); v.y = tanhf(v.y);
        v.z = tanhf(v.z); v.w = tanhf(v.w);
        ((float4*)out)[i] = v;
    }
}

extern "C" void kernel_launch(void* const* d_in, const int* in_sizes, int n_in,
                              void* d_out, int out_size, void* d_ws, size_t ws_size,
                              hipStream_t stream) {
    const float* x    = (const float*)d_in[0];
    const float* W    = (const float*)d_in[1];
    const float* ev   = (const float*)d_in[2];
    const int*   rows = (const int*)d_in[3];
    const int*   cols = (const int*)d_in[4];
    int N = in_sizes[0] / F;
    int E = in_sizes[2];
    float* out = (float*)d_out;
    float* ws  = (float*)d_ws;

    size_t off = 0;
    float* stats = ws + off; off += 256;
    float* Kp    = ws + off; off += F * D;
    float* bias  = ws + off; off += 64;
    off = (off + 255) & ~(size_t)255;

    int nbins = (N + (1 << BSHIFT) - 1) >> BSHIFT;
    int*   bincnt   = (int*)(ws + off);   off += 256;
    int*   binstart = (int*)(ws + off);   off += 257;
    int*   bincur   = (int*)(ws + off);   off += 256;
    off = (off + 255) & ~(size_t)255;
    int*   startm   = (int*)(ws + off);   off += N;
    int*   cnt      = (int*)(ws + off);   off += N;
    off = (off + 255) & ~(size_t)255;
    float2* ce      = (float2*)(ws + off); off += (size_t)2 * E;
    // h region (fp16, N*D*2 B) doubles as ce_tmp (float4[E]); gemm runs AFTER binsortB
    size_t hfloats  = ((size_t)N * D > (size_t)4 * E) ? (size_t)N * D : (size_t)4 * E;
    __half* h       = (__half*)(ws + off); off += hfloats;
    float4* ce_tmp  = (float4*)h;
    size_t need_csr = off * sizeof(float);

    hipMemsetAsync(stats, 0, 256 * sizeof(float), stream);
    k_stats<<<512, 256, 0, stream>>>(x, stats, N);
    k_prep <<<1, 128, 0, stream>>>(stats, W, Kp, bias, N);

    if (need_csr <= ws_size && nbins <= 256) {
        hipMemsetAsync(bincnt, 0, 256 * sizeof(int), stream);
        k_binhist<<<(E + HCHUNK - 1) / HCHUNK, 256, 0, stream>>>(rows, bincnt, E);
        k_binscan<<<1, 256, 0, stream>>>(bincnt, binstart, bincur, E);
        k_blocksortA<<<(E + CHUNK - 1) / CHUNK, 256, 0, stream>>>(rows, cols, ev, bincur, ce_tmp, E);
        k_binsortB<<<nbins, 256, 0, stream>>>(ce_tmp, binstart, startm, cnt, ce, N, E);
        k_gemm<<<N / 32, 256, 0, stream>>>(x, Kp, bias, h, N);   // overwrites ce_tmp (done)
        k_agg <<<(N + 3) / 4, 256, 0, stream>>>(startm, cnt, ce, h, out, N);
    } else {
        size_t o2 = (256 + F * D + 64 + 255) & ~(size_t)255;
        float* rmax = ws + o2;  o2 += N;
        float* rsum = ws + o2;  o2 += N;
        __half* h2  = (__half*)(ws + o2);  o2 += (size_t)N * D / 2 + 64;
        hipMemsetAsync(rmax, 0, (size_t)2 * N * sizeof(float), stream);
        hipMemsetAsync(out, 0, (size_t)out_size * sizeof(float), stream);
        k_gemm  <<<N / 32, 256, 0, stream>>>(x, Kp, bias, h2, N);
        k_rowmax<<<(E + 255) / 256, 256, 0, stream>>>(ev, rows, rmax, E);
        k_rowsum<<<(E + 255) / 256, 256, 0, stream>>>(ev, rows, rmax, rsum, E);
        k_scatter<<<(E + 3) / 4, 256, 0, stream>>>(ev, rows, cols, rmax, rsum, h2, out, E);
        k_tanh  <<<2048, 256, 0, stream>>>(out, (N * D) / 4);
    }
}